// Round 1
// baseline (324.187 us; speedup 1.0000x reference)
//
#include <hip/hip_runtime.h>
#include <cstdint>
#include <cstddef>

#define HDIM 2048
#define NEXP 64
#define HC   16      // h-chunk staged per iteration
#define BTOK 128     // tokens per block
#define PX   132     // LDS pitch for x tile (128 + 4: 2-way bank aliasing = free)
#define PW   68      // LDS pitch for W tile (64 + 4)

// ---------------------------------------------------------------------------
// Kernel 1: partial gate GEMM.  grid = (N/BTOK) * hsplit blocks, 256 threads.
// Each block: 128 tokens x 64 experts over an H-slice of HS.
// Per wave: 32 tokens x 64 experts; per lane: 4 tok x 8 exp accumulators.
// ---------------------------------------------------------------------------
__global__ __launch_bounds__(256) void moe_gemm(const float* __restrict__ x,
                                                const float* __restrict__ W,
                                                float* __restrict__ partial,
                                                int N, int HS) {
  __shared__ __align__(16) float xt[HC][PX];  // [h][tok] transposed
  __shared__ __align__(16) float wt[HC][PW];  // [h][e]

  const int ntb   = N / BTOK;
  const int tb    = blockIdx.x % ntb;
  const int hsIdx = blockIdx.x / ntb;
  const int tok0  = tb * BTOK;
  const int h0    = hsIdx * HS;
  const int tid   = threadIdx.x;
  const int lane  = tid & 63;
  const int wid   = tid >> 6;
  // lane -> (token group, expert group).  e-contiguous lanes for coalesced C-write.
  const int xoff  = wid * 32 + (lane >> 3) * 4;  // token offset within block tile
  const int e0    = (lane & 7) * 8;              // expert offset

  float acc[4][8];
#pragma unroll
  for (int t = 0; t < 4; ++t)
#pragma unroll
    for (int e = 0; e < 8; ++e) acc[t][e] = 0.f;

  const int srow = tid >> 2;       // 0..63
  const int sj   = (tid & 3) * 4;  // 0,4,8,12

  for (int c = 0; c < HS; c += HC) {
    const int hb = h0 + c;
    // stage x chunk (transposed): 2 x (256 thr * float4) = 128 tok x 16 h
#pragma unroll
    for (int i = 0; i < 2; ++i) {
      const int row = srow + i * 64;
      const float4 v = *reinterpret_cast<const float4*>(
          &x[(size_t)(tok0 + row) * HDIM + hb + sj]);
      xt[sj + 0][row] = v.x;
      xt[sj + 1][row] = v.y;
      xt[sj + 2][row] = v.z;
      xt[sj + 3][row] = v.w;
    }
    // stage W chunk: 64 e x 16 h
    {
      const float4 v = *reinterpret_cast<const float4*>(
          &W[(size_t)srow * HDIM + hb + sj]);
      wt[sj + 0][srow] = v.x;
      wt[sj + 1][srow] = v.y;
      wt[sj + 2][srow] = v.z;
      wt[sj + 3][srow] = v.w;
    }
    __syncthreads();
#pragma unroll
    for (int h = 0; h < HC; ++h) {
      const float4 xv = *reinterpret_cast<const float4*>(&xt[h][xoff]);
      const float4 wa = *reinterpret_cast<const float4*>(&wt[h][e0]);
      const float4 wb = *reinterpret_cast<const float4*>(&wt[h][e0 + 4]);
      const float xs[4] = {xv.x, xv.y, xv.z, xv.w};
      const float wv[8] = {wa.x, wa.y, wa.z, wa.w, wb.x, wb.y, wb.z, wb.w};
#pragma unroll
      for (int t = 0; t < 4; ++t)
#pragma unroll
        for (int e = 0; e < 8; ++e)
          acc[t][e] = fmaf(xs[t], wv[e], acc[t][e]);
    }
    __syncthreads();
  }

  // write partial logits: partial[hs][tok][e]
  const size_t base = ((size_t)hsIdx * N + (tok0 + xoff)) * NEXP + e0;
#pragma unroll
  for (int t = 0; t < 4; ++t) {
    const float4 a = make_float4(acc[t][0], acc[t][1], acc[t][2], acc[t][3]);
    const float4 b = make_float4(acc[t][4], acc[t][5], acc[t][6], acc[t][7]);
    *reinterpret_cast<float4*>(&partial[base + (size_t)t * NEXP]) = a;
    *reinterpret_cast<float4*>(&partial[base + (size_t)t * NEXP + 4]) = b;
  }
}

// ---------------------------------------------------------------------------
// Kernel 2: reduce H-splits (deterministic order), softmax, top-2, renorm,
// loss partials.  One wave per token (lane = expert).  grid = N/4, 256 thr.
// ---------------------------------------------------------------------------
__global__ __launch_bounds__(256) void moe_gate(const float* __restrict__ partial,
                                                int N, int hsplit,
                                                float* __restrict__ outS,
                                                float* __restrict__ outI,
                                                float* __restrict__ esumG,
                                                float* __restrict__ lse2G) {
  __shared__ float esum[NEXP];
  __shared__ float lse2s;
  const int tid  = threadIdx.x;
  const int lane = tid & 63;
  const int wid  = tid >> 6;
  if (tid < NEXP) esum[tid] = 0.f;
  if (tid == 0) lse2s = 0.f;
  __syncthreads();

  const int t = blockIdx.x * 4 + wid;
  float logit = 0.f;
  for (int hs = 0; hs < hsplit; ++hs)
    logit += partial[((size_t)hs * N + t) * NEXP + lane];

  // wave softmax over 64 experts
  float m = logit;
#pragma unroll
  for (int d = 1; d < 64; d <<= 1) m = fmaxf(m, __shfl_xor(m, d));
  const float p = expf(logit - m);
  float s = p;
#pragma unroll
  for (int d = 1; d < 64; d <<= 1) s += __shfl_xor(s, d);
  const float score = p / s;

  // top-1 (ties -> lower index, matching jax.lax.top_k)
  float v1 = score;
  int   i1 = lane;
#pragma unroll
  for (int d = 1; d < 64; d <<= 1) {
    const float pv = __shfl_xor(v1, d);
    const int   pi = __shfl_xor(i1, d);
    if (pv > v1 || (pv == v1 && pi < i1)) { v1 = pv; i1 = pi; }
  }
  // top-2: exclude i1 (scores are >= 0, so -1 sentinel is safe)
  float v2 = (lane == i1) ? -1.f : score;
  int   i2 = lane;
#pragma unroll
  for (int d = 1; d < 64; d <<= 1) {
    const float pv = __shfl_xor(v2, d);
    const int   pi = __shfl_xor(i2, d);
    if (pv > v2 || (pv == v2 && pi < i2)) { v2 = pv; i2 = pi; }
  }

  if (lane == 0) {
    // softmax over the two selected scores (as the reference does)
    const float mx  = fmaxf(v1, v2);
    const float e1  = expf(v1 - mx), e2 = expf(v2 - mx);
    const float inv = 1.f / (e1 + e2);
    *reinterpret_cast<float2*>(&outS[2 * (size_t)t]) = make_float2(e1 * inv, e2 * inv);
    *reinterpret_cast<float2*>(&outI[2 * (size_t)t]) = make_float2((float)i1, (float)i2);
  }

  // loss partials
  atomicAdd(&esum[lane], score);           // per-expert score sums
  if (lane == 0) {
    const float lse = m + logf(s);
    atomicAdd(&lse2s, lse * lse);
  }
  __syncthreads();
  if (tid < NEXP) atomicAdd(&esumG[tid], esum[tid]);
  if (tid == 0) atomicAdd(lse2G, lse2s);
}

// ---------------------------------------------------------------------------
// Kernel 3: finalize scalar loss.  1 block, 64 threads.
// ---------------------------------------------------------------------------
__global__ void moe_loss(const float* __restrict__ esumG,
                         const float* __restrict__ lse2G,
                         float* __restrict__ outL, int N) {
  const int lane = threadIdx.x;
  const float load = esumG[lane] / (float)N;
  const float dv   = load - 1.0f / 64.0f;
  float v = dv * dv;
#pragma unroll
  for (int d = 1; d < 64; d <<= 1) v += __shfl_xor(v, d);
  if (lane == 0) outL[0] = 0.01f * v + 1e-4f * (lse2G[0] / (float)N);
}

// ---------------------------------------------------------------------------
extern "C" void kernel_launch(void* const* d_in, const int* in_sizes, int n_in,
                              void* d_out, int out_size, void* d_ws, size_t ws_size,
                              hipStream_t stream) {
  const float* x = (const float*)d_in[0];
  const float* W = (const float*)d_in[1];
  const int N = in_sizes[0] / HDIM;  // 16384

  float* out  = (float*)d_out;
  float* outS = out;                      // [N,2] renormalized top scores
  float* outI = out + (size_t)2 * N;      // [N,2] indices (as float)
  float* outL = out + (size_t)4 * N;      // scalar total loss

  // pick the largest H-split the workspace can hold (occupancy vs ws_size)
  int hsplit = 1;
  for (int h = 8; h >= 1; h >>= 1) {
    const size_t need = (size_t)h * N * NEXP * sizeof(float) + 512;
    if (ws_size >= need) { hsplit = h; break; }
  }
  const int HS = HDIM / hsplit;

  float* partial = (float*)d_ws;                                   // [hsplit][N][64]
  float* esumG   = (float*)((char*)d_ws + (size_t)hsplit * N * NEXP * sizeof(float));
  float* lse2G   = esumG + NEXP;
  hipMemsetAsync(esumG, 0, (NEXP + 1) * sizeof(float), stream);

  const int ntb = N / BTOK;
  moe_gemm<<<dim3(ntb * hsplit), dim3(256), 0, stream>>>(x, W, partial, N, HS);
  moe_gate<<<dim3(N / 4), dim3(256), 0, stream>>>(partial, N, hsplit, outS, outI, esumG, lse2G);
  moe_loss<<<dim3(1), dim3(64), 0, stream>>>(esumG, lse2G, outL, N);
}

// Round 2
// 300.677 us; speedup vs baseline: 1.0782x; 1.0782x over previous
//
#include <hip/hip_runtime.h>
#include <cstdint>
#include <cstddef>

#define HDIM 2048
#define NEXP 64
#define HC   16      // h-chunk staged per iteration
#define BTOK 128     // tokens per gemm block
#define GTHR 128     // gemm threads (2 waves)
#define PX   132     // LDS pitch for x tile (2-way bank aliasing = free)
#define PW   68      // LDS pitch for W tile
#define GATE_TOK 16  // tokens per gate block (4 waves x 4 tokens)

// ---------------------------------------------------------------------------
// Kernel 1: partial gate GEMM, double-buffered LDS, 8tok x 8exp per lane.
// grid = (N/BTOK) * hsplit, 128 threads. Wave tile: 64 tok x 64 exp.
// ---------------------------------------------------------------------------
__global__ __launch_bounds__(GTHR) void moe_gemm(const float* __restrict__ x,
                                                 const float* __restrict__ W,
                                                 float* __restrict__ partial,
                                                 int N, int HS) {
  __shared__ __align__(16) float xt[2][HC][PX];  // [buf][h][tok]
  __shared__ __align__(16) float wt[2][HC][PW];  // [buf][h][e]

  const int ntb   = N / BTOK;
  const int tb    = blockIdx.x % ntb;
  const int hsIdx = blockIdx.x / ntb;
  const int tok0  = tb * BTOK;
  const int h0    = hsIdx * HS;
  const int tid   = threadIdx.x;
  const int lane  = tid & 63;
  const int wid   = tid >> 6;
  const int xoff  = wid * 64 + (lane >> 3) * 8;  // 8-token group
  const int e0    = (lane & 7) * 8;              // 8-expert group
  const int srow  = tid >> 2;                    // 0..31
  const int sj    = (tid & 3) * 4;               // 0,4,8,12

  float acc[8][8];
#pragma unroll
  for (int t = 0; t < 8; ++t)
#pragma unroll
    for (int e = 0; e < 8; ++e) acc[t][e] = 0.f;

  float4 xr[4], wr[2];

  // prologue: load + stage chunk 0
#pragma unroll
  for (int i = 0; i < 4; ++i)
    xr[i] = *reinterpret_cast<const float4*>(&x[(size_t)(tok0 + srow + i * 32) * HDIM + h0 + sj]);
#pragma unroll
  for (int i = 0; i < 2; ++i)
    wr[i] = *reinterpret_cast<const float4*>(&W[(size_t)(srow + i * 32) * HDIM + h0 + sj]);
#pragma unroll
  for (int i = 0; i < 4; ++i) {
    const int r = srow + i * 32;
    xt[0][sj + 0][r] = xr[i].x; xt[0][sj + 1][r] = xr[i].y;
    xt[0][sj + 2][r] = xr[i].z; xt[0][sj + 3][r] = xr[i].w;
  }
#pragma unroll
  for (int i = 0; i < 2; ++i) {
    const int r = srow + i * 32;
    wt[0][sj + 0][r] = wr[i].x; wt[0][sj + 1][r] = wr[i].y;
    wt[0][sj + 2][r] = wr[i].z; wt[0][sj + 3][r] = wr[i].w;
  }
  __syncthreads();

  const int niter = HS / HC;
  int cur = 0;
  for (int c = 0; c < niter; ++c) {
    // issue next chunk's global loads before compute (latency hides under FMAs)
    if (c + 1 < niter) {
      const int hb = h0 + (c + 1) * HC;
#pragma unroll
      for (int i = 0; i < 4; ++i)
        xr[i] = *reinterpret_cast<const float4*>(&x[(size_t)(tok0 + srow + i * 32) * HDIM + hb + sj]);
#pragma unroll
      for (int i = 0; i < 2; ++i)
        wr[i] = *reinterpret_cast<const float4*>(&W[(size_t)(srow + i * 32) * HDIM + hb + sj]);
    }
    // compute on current buffer
#pragma unroll
    for (int h = 0; h < HC; ++h) {
      const float4 a0 = *reinterpret_cast<const float4*>(&xt[cur][h][xoff]);
      const float4 a1 = *reinterpret_cast<const float4*>(&xt[cur][h][xoff + 4]);
      const float4 b0 = *reinterpret_cast<const float4*>(&wt[cur][h][e0]);
      const float4 b1 = *reinterpret_cast<const float4*>(&wt[cur][h][e0 + 4]);
      const float xs[8] = {a0.x, a0.y, a0.z, a0.w, a1.x, a1.y, a1.z, a1.w};
      const float wv[8] = {b0.x, b0.y, b0.z, b0.w, b1.x, b1.y, b1.z, b1.w};
#pragma unroll
      for (int t = 0; t < 8; ++t)
#pragma unroll
        for (int e = 0; e < 8; ++e)
          acc[t][e] = fmaf(xs[t], wv[e], acc[t][e]);
    }
    // stage next chunk into the other buffer
    if (c + 1 < niter) {
      const int nx = cur ^ 1;
#pragma unroll
      for (int i = 0; i < 4; ++i) {
        const int r = srow + i * 32;
        xt[nx][sj + 0][r] = xr[i].x; xt[nx][sj + 1][r] = xr[i].y;
        xt[nx][sj + 2][r] = xr[i].z; xt[nx][sj + 3][r] = xr[i].w;
      }
#pragma unroll
      for (int i = 0; i < 2; ++i) {
        const int r = srow + i * 32;
        wt[nx][sj + 0][r] = wr[i].x; wt[nx][sj + 1][r] = wr[i].y;
        wt[nx][sj + 2][r] = wr[i].z; wt[nx][sj + 3][r] = wr[i].w;
      }
    }
    __syncthreads();
    cur ^= 1;
  }

  // write partial logits: partial[hs][tok][e]
  const size_t base = ((size_t)hsIdx * N + (tok0 + xoff)) * NEXP + e0;
#pragma unroll
  for (int t = 0; t < 8; ++t) {
    *reinterpret_cast<float4*>(&partial[base + (size_t)t * NEXP]) =
        make_float4(acc[t][0], acc[t][1], acc[t][2], acc[t][3]);
    *reinterpret_cast<float4*>(&partial[base + (size_t)t * NEXP + 4]) =
        make_float4(acc[t][4], acc[t][5], acc[t][6], acc[t][7]);
  }
}

// ---------------------------------------------------------------------------
// Kernel 2: reduce H-splits, softmax, top-2, renorm; per-block loss partials
// (registers -> LDS -> one ws slot per block; NO global atomics).
// grid = N/GATE_TOK blocks, 256 threads (4 waves x 4 tokens each).
// ---------------------------------------------------------------------------
template <int HSPLIT>
__global__ __launch_bounds__(256) void moe_gate(const float* __restrict__ partial,
                                                int N,
                                                float* __restrict__ outS,
                                                float* __restrict__ outI,
                                                float* __restrict__ esumP,
                                                float* __restrict__ lse2P) {
  __shared__ float es[4][NEXP];
  __shared__ float l2[4];
  const int tid  = threadIdx.x;
  const int lane = tid & 63;
  const int w    = tid >> 6;
  const int base = blockIdx.x * GATE_TOK + w * 4;

  float esum = 0.f, lse2 = 0.f;
#pragma unroll
  for (int tt = 0; tt < 4; ++tt) {
    const int t = base + tt;
    float logit = 0.f;
#pragma unroll
    for (int hs = 0; hs < HSPLIT; ++hs)
      logit += partial[((size_t)hs * N + t) * NEXP + lane];

    // wave softmax over 64 experts
    float m = logit;
#pragma unroll
    for (int d = 1; d < 64; d <<= 1) m = fmaxf(m, __shfl_xor(m, d));
    const float p = expf(logit - m);
    float s = p;
#pragma unroll
    for (int d = 1; d < 64; d <<= 1) s += __shfl_xor(s, d);
    const float score = p / s;

    // top-1 (ties -> lower index)
    float v1 = score; int i1 = lane;
#pragma unroll
    for (int d = 1; d < 64; d <<= 1) {
      const float pv = __shfl_xor(v1, d);
      const int   pi = __shfl_xor(i1, d);
      if (pv > v1 || (pv == v1 && pi < i1)) { v1 = pv; i1 = pi; }
    }
    // top-2 excluding i1 (scores >= 0)
    float v2 = (lane == i1) ? -1.f : score; int i2 = lane;
#pragma unroll
    for (int d = 1; d < 64; d <<= 1) {
      const float pv = __shfl_xor(v2, d);
      const int   pi = __shfl_xor(i2, d);
      if (pv > v2 || (pv == v2 && pi < i2)) { v2 = pv; i2 = pi; }
    }

    if (lane == 0) {
      const float mx  = fmaxf(v1, v2);
      const float e1  = expf(v1 - mx), e2 = expf(v2 - mx);
      const float inv = 1.f / (e1 + e2);
      *reinterpret_cast<float2*>(&outS[2 * (size_t)t]) = make_float2(e1 * inv, e2 * inv);
      *reinterpret_cast<float2*>(&outI[2 * (size_t)t]) = make_float2((float)i1, (float)i2);
    }

    esum += score;                       // this lane's expert, this token
    const float lse = m + logf(s);       // identical in all lanes
    lse2 += lse * lse;
  }

  es[w][lane] = esum;
  if (lane == 0) l2[w] = lse2;
  __syncthreads();
  if (tid < NEXP)
    esumP[(size_t)blockIdx.x * NEXP + tid] = es[0][tid] + es[1][tid] + es[2][tid] + es[3][tid];
  if (tid == 0)
    lse2P[blockIdx.x] = l2[0] + l2[1] + l2[2] + l2[3];
}

// ---------------------------------------------------------------------------
// Kernel 3: reduce per-block partials, finalize scalar loss. 1 block, 256 thr.
// ---------------------------------------------------------------------------
__global__ __launch_bounds__(256) void moe_loss(const float* __restrict__ esumP,
                                                const float* __restrict__ lse2P,
                                                float* __restrict__ outL,
                                                int N, int nb) {
  __shared__ float es[4][NEXP];
  __shared__ float l2s[4];
  const int tid = threadIdx.x, lane = tid & 63, w = tid >> 6;

  float acc = 0.f;
  for (int b = w; b < nb; b += 4) acc += esumP[(size_t)b * NEXP + lane];
  es[w][lane] = acc;

  float la = 0.f;
  for (int b = tid; b < nb; b += 256) la += lse2P[b];
#pragma unroll
  for (int d = 1; d < 64; d <<= 1) la += __shfl_xor(la, d);
  if (lane == 0) l2s[w] = la;
  __syncthreads();

  if (tid < NEXP) {
    const float tot  = es[0][tid] + es[1][tid] + es[2][tid] + es[3][tid];
    const float load = tot / (float)N;
    const float dv   = load - 1.0f / 64.0f;
    float q = dv * dv;
#pragma unroll
    for (int d = 1; d < 64; d <<= 1) q += __shfl_xor(q, d);
    if (tid == 0) {
      const float lseSum = l2s[0] + l2s[1] + l2s[2] + l2s[3];
      outL[0] = 0.01f * q + 1e-4f * (lseSum / (float)N);
    }
  }
}

// ---------------------------------------------------------------------------
extern "C" void kernel_launch(void* const* d_in, const int* in_sizes, int n_in,
                              void* d_out, int out_size, void* d_ws, size_t ws_size,
                              hipStream_t stream) {
  const float* x = (const float*)d_in[0];
  const float* W = (const float*)d_in[1];
  const int N  = in_sizes[0] / HDIM;   // 16384
  const int GB = N / GATE_TOK;         // 1024 gate blocks

  float* out  = (float*)d_out;
  float* outS = out;                   // [N,2] renormalized top scores
  float* outI = out + (size_t)2 * N;   // [N,2] indices (as float)
  float* outL = out + (size_t)4 * N;   // scalar total loss

  // pick the largest H-split the workspace can hold
  int hsplit = 1;
  for (int h = 8; h >= 1; h >>= 1) {
    const size_t need = (size_t)h * N * NEXP * sizeof(float)
                      + (size_t)GB * (NEXP + 1) * sizeof(float) + 256;
    if (ws_size >= need) { hsplit = h; break; }
  }
  const int HS = HDIM / hsplit;

  float* partial = (float*)d_ws;  // [hsplit][N][64]
  float* esumP   = (float*)((char*)d_ws + (size_t)hsplit * N * NEXP * sizeof(float));
  float* lse2P   = esumP + (size_t)GB * NEXP;

  const int ntb = N / BTOK;
  moe_gemm<<<dim3(ntb * hsplit), dim3(GTHR), 0, stream>>>(x, W, partial, N, HS);
  switch (hsplit) {
    case 8: moe_gate<8><<<dim3(GB), dim3(256), 0, stream>>>(partial, N, outS, outI, esumP, lse2P); break;
    case 4: moe_gate<4><<<dim3(GB), dim3(256), 0, stream>>>(partial, N, outS, outI, esumP, lse2P); break;
    case 2: moe_gate<2><<<dim3(GB), dim3(256), 0, stream>>>(partial, N, outS, outI, esumP, lse2P); break;
    default: moe_gate<1><<<dim3(GB), dim3(256), 0, stream>>>(partial, N, outS, outI, esumP, lse2P); break;
  }
  moe_loss<<<dim3(1), dim3(256), 0, stream>>>(esumP, lse2P, outL, N, GB);
}